// Round 7
// baseline (158.271 us; speedup 1.0000x reference)
//
#include <hip/hip_runtime.h>
#include <stdint.h>

// Problem constants (fixed by reference file)
#define N_NODES 50000
#define KDEG    16
#define NFEAT   128
#define NTPL    16
#define MTPL    8
#define NTILES2 ((N_NODES + 127) / 128)   // zbuild: 128 rows per block

// Workspace layout (floats):
//   [0    .. 2047]  tmean[t*128 + f]        (fallback path only)
//   [2048 .. 2063]  tsq[t]
//   [2064 .. 2079]  mCt[t]
//   [2080 .. 2095]  mCt2[t]
//   [2112 .. ]      z[n*16 + t] = 0.5*s2[n] - x[n]·tmean_t
#define TMEAN_OFF 0
#define TSQ_OFF   2048
#define MCT_OFF   2064
#define MCT2_OFF  2080
#define Z_OFF     2112
#define WS_FLOATS (Z_OFF + N_NODES * NTPL)
#define WS_BYTES  ((size_t)WS_FLOATS * 4)

// ---- DPP reduction helpers (VALU pipe, no LDS) ------------------------------
// row_ror:n rotates within each 16-lane DPP row; 4 rotates = full row sum.
// quad_perm 0xB1 = lane^1, 0x4E = lane^2 (within each quad).
template<int CTRL>
__device__ __forceinline__ float dpp_addf(float v) {
    int t = __builtin_amdgcn_update_dpp(0, __float_as_int(v), CTRL, 0xF, 0xF, 1);
    return v + __int_as_float(t);
}
template<int CTRL>
__device__ __forceinline__ int dpp_addi(int v) {
    int t = __builtin_amdgcn_update_dpp(0, v, CTRL, 0xF, 0xF, 1);
    return v + t;
}
#define ROR1 0x121
#define ROR2 0x122
#define ROR4 0x124
#define ROR8 0x128
#define QPX1 0xB1
#define QPX2 0x4E

__device__ __forceinline__ float row16_sum(float v) {   // sum over 16-lane row
    v = dpp_addf<ROR1>(v);
    v = dpp_addf<ROR2>(v);
    v = dpp_addf<ROR4>(v);
    v = dpp_addf<ROR8>(v);
    return v;
}
__device__ __forceinline__ int row16_sumi(int v) {
    v = dpp_addi<ROR1>(v);
    v = dpp_addi<ROR2>(v);
    v = dpp_addi<ROR4>(v);
    v = dpp_addi<ROR8>(v);
    return v;
}
__device__ __forceinline__ float quad_sum(float v) {    // sum over 4-lane quad
    v = dpp_addf<QPX1>(v);
    v = dpp_addf<QPX2>(v);
    return v;
}

// ============ Kernel A: template stats (per-block, redundant) + z table ======
__global__ __launch_bounds__(256, 3)
void ltfwg_zbuild(const float* __restrict__ x,      // [N,128]
                  const float* __restrict__ tmpl,   // [16,8,8]
                  const float* __restrict__ tfeat,  // [16,8,128]
                  float* __restrict__ ws) {
    const int tid = threadIdx.x;

    // tmean in LDS, skewed [t][q][36]: bank(t*144+q*36+4j) = (16t+4q+4j)%32
    __shared__ float tm_lds[NTPL * 144];

    {   // all 256 threads: thread (f = tid&127, half = tid>>7) does 8 templates
        const int f  = tid & 127;
        const int t0 = (tid >> 7) * 8;
        #pragma unroll
        for (int k = 0; k < 8; ++k) {
            int t = t0 + k;
            float s = 0.f;
            #pragma unroll
            for (int m = 0; m < MTPL; ++m)
                s += tfeat[t * (MTPL * NFEAT) + m * NFEAT + f];
            tm_lds[t * 144 + (f >> 5) * 36 + (f & 31)] = s * 0.125f;
        }
    }

    // Block 0 additionally computes the 48 scalar stats kernel B needs.
    if (blockIdx.x == 0) {
        const int t = tid >> 4;      // 16 threads per template
        const int j = tid & 15;
        float ssq = 0.f;
        #pragma unroll
        for (int m = 0; m < MTPL; ++m)
            #pragma unroll
            for (int c = 0; c < 8; ++c) {
                float v = tfeat[t * (MTPL * NFEAT) + m * NFEAT + j * 8 + c];
                ssq += v * v;
            }
        float sv = 0.f, sv2 = 0.f;
        #pragma unroll
        for (int c = 0; c < 4; ++c) {
            float v = tmpl[t * 64 + j * 4 + c];
            sv += v;
            sv2 += v * v;
        }
        ssq = row16_sum(ssq);
        sv  = row16_sum(sv);
        sv2 = row16_sum(sv2);
        if (j == 0) {
            ws[TSQ_OFF + t]  = ssq * 0.125f;
            ws[MCT_OFF + t]  = sv  * (1.f / 64.f);
            ws[MCT2_OFF + t] = sv2 * (1.f / 64.f);
        }
    }
    __syncthreads();

    // z phase: 4 lanes per row (q = feature quarter), 2 rows per lane
    const int q  = tid & 3;
    const int rr = tid >> 2;          // 0..63
    for (int tile = blockIdx.x; tile < NTILES2; tile += gridDim.x) {
        const int n0 = tile * 128 + rr;
        const int n1 = n0 + 64;
        const bool ok0 = (n0 < N_NODES), ok1 = (n1 < N_NODES);

        float4 xa[8], xb[8];
        if (ok0) {
            const float4* x4 = (const float4*)x + (size_t)n0 * 32 + q * 8;
            #pragma unroll
            for (int jj = 0; jj < 8; ++jj) xa[jj] = x4[jj];
        }
        if (ok1) {
            const float4* x4 = (const float4*)x + (size_t)n1 * 32 + q * 8;
            #pragma unroll
            for (int jj = 0; jj < 8; ++jj) xb[jj] = x4[jj];
        }
        if (!ok0) break;

        float s2a = 0.f, s2b = 0.f;
        #pragma unroll
        for (int jj = 0; jj < 8; ++jj) {
            s2a += xa[jj].x * xa[jj].x + xa[jj].y * xa[jj].y +
                   xa[jj].z * xa[jj].z + xa[jj].w * xa[jj].w;
            if (ok1)
                s2b += xb[jj].x * xb[jj].x + xb[jj].y * xb[jj].y +
                       xb[jj].z * xb[jj].z + xb[jj].w * xb[jj].w;
        }

        float acc0[NTPL], acc1[NTPL];
        #pragma unroll
        for (int t = 0; t < NTPL; ++t) {
            const float* tb = tm_lds + t * 144 + q * 36;
            float a0 = 0.f, a1 = 0.f;
            #pragma unroll
            for (int jj = 0; jj < 8; ++jj) {
                float4 tv = *(const float4*)(tb + 4 * jj);   // shared by both rows
                a0 += xa[jj].x * tv.x + xa[jj].y * tv.y +
                      xa[jj].z * tv.z + xa[jj].w * tv.w;
                a1 += xb[jj].x * tv.x + xb[jj].y * tv.y +
                      xb[jj].z * tv.z + xb[jj].w * tv.w;
            }
            acc0[t] = a0;
            acc1[t] = a1;
        }

        float h0 = quad_sum(s2a) * 0.5f;
        float h1 = quad_sum(s2b) * 0.5f;
        #pragma unroll
        for (int t = 0; t < NTPL; ++t) {
            acc0[t] = quad_sum(acc0[t]);
            acc1[t] = quad_sum(acc1[t]);
        }

        // lane q writes chunk q of each row: coalesced
        float a0, a1, a2, a3, b0, b1, b2, b3;
        if (q == 0)      { a0=acc0[0];  a1=acc0[1];  a2=acc0[2];  a3=acc0[3];
                           b0=acc1[0];  b1=acc1[1];  b2=acc1[2];  b3=acc1[3];  }
        else if (q == 1) { a0=acc0[4];  a1=acc0[5];  a2=acc0[6];  a3=acc0[7];
                           b0=acc1[4];  b1=acc1[5];  b2=acc1[6];  b3=acc1[7];  }
        else if (q == 2) { a0=acc0[8];  a1=acc0[9];  a2=acc0[10]; a3=acc0[11];
                           b0=acc1[8];  b1=acc1[9];  b2=acc1[10]; b3=acc1[11]; }
        else             { a0=acc0[12]; a1=acc0[13]; a2=acc0[14]; a3=acc0[15];
                           b0=acc1[12]; b1=acc1[13]; b2=acc1[14]; b3=acc1[15]; }
        ((float4*)(ws + Z_OFF))[(size_t)n0 * 4 + q] =
            make_float4(h0 - a0, h0 - a1, h0 - a2, h0 - a3);
        if (ok1)
            ((float4*)(ws + Z_OFF))[(size_t)n1 * 4 + q] =
                make_float4(h1 - b0, h1 - b1, h1 - b2, h1 - b3);
    }
}

// ============ Kernel B: per-node gather + structure ==========================
// Lane mapping: a = lane&15 (neighbor slot), c = lane>>4 (16B chunk).
// z-gather and dst-row load use the lane's OWN nbr (independent loads).
// All intra-row reductions via DPP (VALU); only the 2 chunk-merges use DS.
__global__ __launch_bounds__(256, 8)
void ltfwg_gather(const int* __restrict__ dst, const float* __restrict__ ws,
                  float* __restrict__ out) {
    const int lane   = threadIdx.x & 63;
    const int gwave  = (blockIdx.x * blockDim.x + threadIdx.x) >> 6;
    const int nwaves = (gridDim.x * blockDim.x) >> 6;
    const int a = lane & 15;
    const int c = lane >> 4;

    const int tl = c * 4 + (lane & 3);
    const float A  = 0.5f * (ws[TSQ_OFF + tl] + ws[MCT2_OFF + tl]);
    const float Bc = 0.5f - ws[MCT_OFF + tl];
    const bool writer = (lane & 15) < 4;
    const float4* z4 = (const float4*)(ws + Z_OFF);
    const int4*  d4 = (const int4*)dst;

    int n = gwave;
    int nbr = (n < N_NODES) ? dst[n * KDEG + a] : 0;
    while (n < N_NODES) {
        const int n2 = n + nwaves;
        int nbr_next = (n2 < N_NODES) ? dst[n2 * KDEG + a] : 0;

        // independent loads: z chunk + dst-row chunk of this lane's neighbor
        float4 v  = z4[(size_t)nbr * 4 + c];
        int4   cv = d4[(size_t)nbr * 4 + c];

        // membership mask: bit b = any(cv == nbr_b), partial over this chunk
        uint32_t m = 0;
        #pragma unroll
        for (int b = 0; b < KDEG; ++b) {
            int vb = __builtin_amdgcn_readlane(nbr, b);
            uint32_t hit = (uint32_t)((cv.x == vb) | (cv.y == vb) |
                                      (cv.z == vb) | (cv.w == vb));
            m |= hit << b;
        }
        // merge the 4 chunks of row a (lanes differing in bits 4,5) — DS
        m |= (uint32_t)__shfl_xor((int)m, 16);
        m |= (uint32_t)__shfl_xor((int)m, 32);
        int cm = row16_sumi(__popc(m));        // sum rowcounts over the 16 a's

        // z reduction over a within each 16-lane row — DPP
        float v0 = row16_sum(v.x);
        float v1 = row16_sum(v.y);
        float v2 = row16_sum(v.z);
        float v3 = row16_sum(v.w);

        if (writer) {
            int j = lane & 3;
            float dsel = (j == 0) ? v0 : (j == 1) ? v1 : (j == 2) ? v2 : v3;
            float val = 0.0625f * dsel + A + (float)cm * (1.f / 256.f) * Bc;
            out[n * NTPL + tl] = val;
        }
        n = n2;
        nbr = nbr_next;
    }
}

// ---------------- fallback path (proven R2 kernels, ws too small) ------------
__global__ void ltfwg_prep(const float* __restrict__ tmpl,
                           const float* __restrict__ tfeat,
                           float* __restrict__ ws) {
    const int t   = blockIdx.x;
    const int tid = threadIdx.x;
    float s = 0.f, ssq = 0.f;
    #pragma unroll
    for (int m = 0; m < MTPL; ++m) {
        float v = tfeat[t * (MTPL * NFEAT) + m * NFEAT + tid];
        s += v;
        ssq += v * v;
    }
    ws[TMEAN_OFF + t * NFEAT + tid] = s * 0.125f;
    __shared__ float red[128];
    red[tid] = ssq;
    __syncthreads();
    for (int o = 64; o > 0; o >>= 1) {
        if (tid < o) red[tid] += red[tid + o];
        __syncthreads();
    }
    if (tid == 0) ws[TSQ_OFF + t] = red[0] * 0.125f;
    if (tid < 64) {
        float v = tmpl[t * 64 + tid];
        float sv = v, sv2 = v * v;
        #pragma unroll
        for (int off = 32; off >= 1; off >>= 1) {
            sv  += __shfl_xor(sv, off);
            sv2 += __shfl_xor(sv2, off);
        }
        if (tid == 0) {
            ws[MCT_OFF + t]  = sv  * (1.f / 64.f);
            ws[MCT2_OFF + t] = sv2 * (1.f / 64.f);
        }
    }
}

__global__ __launch_bounds__(256, 4)
void ltfwg_fallback(const float* __restrict__ x, const int* __restrict__ dst,
                    const float* __restrict__ ws, float* __restrict__ out) {
    const int lane   = threadIdx.x & 63;
    const int wave   = (blockIdx.x * blockDim.x + threadIdx.x) >> 6;
    const int nwaves = (gridDim.x * blockDim.x) >> 6;
    float tm0[NTPL], tm1[NTPL];
    #pragma unroll
    for (int t = 0; t < NTPL; ++t) {
        float2 tv = ((const float2*)(ws + TMEAN_OFF + t * NFEAT))[lane];
        tm0[t] = tv.x;
        tm1[t] = tv.y;
    }
    const int tl = lane & 15;
    const float A  = 0.5f * (ws[TSQ_OFF + tl] + ws[MCT2_OFF + tl]);
    const float Bc = 0.5f - ws[MCT_OFF + tl];
    for (int n = wave; n < N_NODES; n += nwaves) {
        const int nbr = dst[n * KDEG + (lane & 15)];
        float fs0 = 0.f, fs1 = 0.f, sqa = 0.f;
        #pragma unroll
        for (int aa = 0; aa < KDEG; ++aa) {
            int nid = __shfl(nbr, aa);
            float2 fv = ((const float2*)x)[nid * (NFEAT / 2) + lane];
            fs0 += fv.x; fs1 += fv.y;
            sqa += fv.x * fv.x + fv.y * fv.y;
        }
        float dotp[NTPL];
        #pragma unroll
        for (int t = 0; t < NTPL; ++t) dotp[t] = fs0 * tm0[t] + fs1 * tm1[t];
        int nida = __shfl(nbr, lane >> 2);
        int4 cv = ((const int4*)(dst + nida * KDEG))[lane & 3];
        uint32_t m = 0;
        #pragma unroll
        for (int b = 0; b < KDEG; ++b) {
            int vb = __shfl(nbr, b);
            uint32_t hit = (uint32_t)((cv.x == vb) | (cv.y == vb) |
                                      (cv.z == vb) | (cv.w == vb));
            m |= hit << b;
        }
        m |= (uint32_t)__shfl_xor((int)m, 1);
        m |= (uint32_t)__shfl_xor((int)m, 2);
        float cnt = (float)__popc(m);
        #pragma unroll
        for (int off = 32; off >= 1; off >>= 1) {
            sqa += __shfl_xor(sqa, off);
            cnt += __shfl_xor(cnt, off);
            #pragma unroll
            for (int t = 0; t < NTPL; ++t) dotp[t] += __shfl_xor(dotp[t], off);
        }
        float dsel = dotp[0];
        #pragma unroll
        for (int t = 1; t < NTPL; ++t) dsel = (lane == t) ? dotp[t] : dsel;
        if (lane < NTPL) {
            float mC = cnt * (1.0f / 1024.0f);
            out[n * NTPL + lane] = 0.03125f * sqa - 0.0625f * dsel + A + mC * Bc;
        }
    }
}

extern "C" void kernel_launch(void* const* d_in, const int* in_sizes, int n_in,
                              void* d_out, int out_size, void* d_ws, size_t ws_size,
                              hipStream_t stream) {
    const float* x     = (const float*)d_in[0];
    const int*   edge  = (const int*)d_in[1];
    const float* tmpl  = (const float*)d_in[2];
    const float* tfeat = (const float*)d_in[3];
    float* ws  = (float*)d_ws;
    float* out = (float*)d_out;
    const int* dst = edge + (N_NODES * KDEG);

    if (ws_size >= WS_BYTES) {
        ltfwg_zbuild<<<NTILES2, 256, 0, stream>>>(x, tmpl, tfeat, ws);
        ltfwg_gather<<<2048, 256, 0, stream>>>(dst, ws, out);
    } else {
        ltfwg_prep<<<NTPL, 128, 0, stream>>>(tmpl, tfeat, ws);
        ltfwg_fallback<<<1024, 256, 0, stream>>>(x, dst, ws, out);
    }
}

// Round 8
// 103.039 us; speedup vs baseline: 1.5360x; 1.5360x over previous
//
#include <hip/hip_runtime.h>
#include <stdint.h>

// Problem constants (fixed by reference file)
#define N_NODES 50000
#define KDEG    16
#define NFEAT   128
#define NTPL    16
#define MTPL    8
#define NTILES  ((N_NODES + 63) / 64)     // zbuild: 64 rows per block

// Workspace layout (floats):
//   [0    .. 2047]  tmean[t*128 + f]        (fallback path only)
//   [2048 .. 2063]  tsq[t]
//   [2064 .. 2079]  mCt[t]
//   [2080 .. 2095]  mCt2[t]
//   [2112 .. ]      z[n*16 + t] = 0.5*s2[n] - x[n]·tmean_t
#define TMEAN_OFF 0
#define TSQ_OFF   2048
#define MCT_OFF   2064
#define MCT2_OFF  2080
#define Z_OFF     2112
#define WS_FLOATS (Z_OFF + N_NODES * NTPL)
#define WS_BYTES  ((size_t)WS_FLOATS * 4)

// ---- DPP reduction helpers (VALU pipe, no LDS) ------------------------------
template<int CTRL>
__device__ __forceinline__ float dpp_addf(float v) {
    int t = __builtin_amdgcn_update_dpp(0, __float_as_int(v), CTRL, 0xF, 0xF, 1);
    return v + __int_as_float(t);
}
template<int CTRL>
__device__ __forceinline__ int dpp_addi(int v) {
    int t = __builtin_amdgcn_update_dpp(0, v, CTRL, 0xF, 0xF, 1);
    return v + t;
}
#define ROR1 0x121
#define ROR2 0x122
#define ROR4 0x124
#define ROR8 0x128
#define QPX1 0xB1
#define QPX2 0x4E

__device__ __forceinline__ float row16_sum(float v) {   // sum over 16-lane row
    v = dpp_addf<ROR1>(v);
    v = dpp_addf<ROR2>(v);
    v = dpp_addf<ROR4>(v);
    v = dpp_addf<ROR8>(v);
    return v;
}
__device__ __forceinline__ int row16_sumi(int v) {
    v = dpp_addi<ROR1>(v);
    v = dpp_addi<ROR2>(v);
    v = dpp_addi<ROR4>(v);
    v = dpp_addi<ROR8>(v);
    return v;
}
__device__ __forceinline__ float quad_sum(float v) {    // sum over 4-lane quad
    v = dpp_addf<QPX1>(v);
    v = dpp_addf<QPX2>(v);
    return v;
}

// ============ Kernel A: template stats (per-block, redundant) + z table ======
// R6-proven shape: 1 row per 4 lanes, xv[8]+acc[16] ~ 84 VGPR, NO SPILLS.
__global__ __launch_bounds__(256, 4)
void ltfwg_zbuild(const float* __restrict__ x,      // [N,128]
                  const float* __restrict__ tmpl,   // [16,8,8]
                  const float* __restrict__ tfeat,  // [16,8,128]
                  float* __restrict__ ws) {
    const int tid = threadIdx.x;

    // tmean in LDS, skewed [t][q][36]: bank(t*144+q*36+4j) = (16t+4q+4j)%32
    __shared__ float tm_lds[NTPL * 144];

    {   // all 256 threads: thread (f = tid&127, half = tid>>7) does 8 templates
        const int f  = tid & 127;
        const int t0 = (tid >> 7) * 8;
        #pragma unroll
        for (int k = 0; k < 8; ++k) {
            int t = t0 + k;
            float s = 0.f;
            #pragma unroll
            for (int m = 0; m < MTPL; ++m)
                s += tfeat[t * (MTPL * NFEAT) + m * NFEAT + f];
            tm_lds[t * 144 + (f >> 5) * 36 + (f & 31)] = s * 0.125f;
        }
    }

    // Block 0 additionally computes the 48 scalar stats kernel B needs.
    if (blockIdx.x == 0) {
        const int t = tid >> 4;      // 16 threads per template
        const int j = tid & 15;
        float ssq = 0.f;
        #pragma unroll
        for (int m = 0; m < MTPL; ++m)
            #pragma unroll
            for (int c = 0; c < 8; ++c) {
                float v = tfeat[t * (MTPL * NFEAT) + m * NFEAT + j * 8 + c];
                ssq += v * v;
            }
        float sv = 0.f, sv2 = 0.f;
        #pragma unroll
        for (int c = 0; c < 4; ++c) {
            float v = tmpl[t * 64 + j * 4 + c];
            sv += v;
            sv2 += v * v;
        }
        ssq = row16_sum(ssq);
        sv  = row16_sum(sv);
        sv2 = row16_sum(sv2);
        if (j == 0) {
            ws[TSQ_OFF + t]  = ssq * 0.125f;
            ws[MCT_OFF + t]  = sv  * (1.f / 64.f);
            ws[MCT2_OFF + t] = sv2 * (1.f / 64.f);
        }
    }
    __syncthreads();

    // z phase: 4 lanes per row (q = feature quarter), 64 rows per tile
    const int q  = tid & 3;
    const int rr = tid >> 2;
    for (int tile = blockIdx.x; tile < NTILES; tile += gridDim.x) {
        int n = tile * 64 + rr;
        if (n < N_NODES) {
            const float4* x4 = (const float4*)x + (size_t)n * 32 + q * 8;
            float4 xv[8];
            #pragma unroll
            for (int jj = 0; jj < 8; ++jj) xv[jj] = x4[jj];

            float s2 = 0.f;
            #pragma unroll
            for (int jj = 0; jj < 8; ++jj)
                s2 += xv[jj].x * xv[jj].x + xv[jj].y * xv[jj].y +
                      xv[jj].z * xv[jj].z + xv[jj].w * xv[jj].w;

            float acc[NTPL];
            #pragma unroll
            for (int t = 0; t < NTPL; ++t) {
                const float* tb = tm_lds + t * 144 + q * 36;
                float a = 0.f;
                #pragma unroll
                for (int jj = 0; jj < 8; ++jj) {
                    float4 tv = *(const float4*)(tb + 4 * jj);
                    a += xv[jj].x * tv.x + xv[jj].y * tv.y +
                         xv[jj].z * tv.z + xv[jj].w * tv.w;
                }
                acc[t] = a;
            }

            float h = quad_sum(s2) * 0.5f;
            #pragma unroll
            for (int t = 0; t < NTPL; ++t) acc[t] = quad_sum(acc[t]);

            float b0, b1, b2, b3;
            if (q == 0)      { b0 = acc[0];  b1 = acc[1];  b2 = acc[2];  b3 = acc[3];  }
            else if (q == 1) { b0 = acc[4];  b1 = acc[5];  b2 = acc[6];  b3 = acc[7];  }
            else if (q == 2) { b0 = acc[8];  b1 = acc[9];  b2 = acc[10]; b3 = acc[11]; }
            else             { b0 = acc[12]; b1 = acc[13]; b2 = acc[14]; b3 = acc[15]; }
            ((float4*)(ws + Z_OFF))[(size_t)n * 4 + q] =
                make_float4(h - b0, h - b1, h - b2, h - b3);
        }
    }
}

// ============ Kernel B: per-node gather + structure ==========================
// Lane mapping: a = lane&15 (neighbor slot), c = lane>>4 (16B chunk).
// z-gather and dst-row load use the lane's OWN nbr (independent loads).
// All intra-row reductions via DPP (VALU); only the 2 chunk-merges use DS.
__global__ __launch_bounds__(256, 8)
void ltfwg_gather(const int* __restrict__ dst, const float* __restrict__ ws,
                  float* __restrict__ out) {
    const int lane   = threadIdx.x & 63;
    const int gwave  = (blockIdx.x * blockDim.x + threadIdx.x) >> 6;
    const int nwaves = (gridDim.x * blockDim.x) >> 6;
    const int a = lane & 15;
    const int c = lane >> 4;

    const int tl = c * 4 + (lane & 3);
    const float A  = 0.5f * (ws[TSQ_OFF + tl] + ws[MCT2_OFF + tl]);
    const float Bc = 0.5f - ws[MCT_OFF + tl];
    const bool writer = (lane & 15) < 4;
    const float4* z4 = (const float4*)(ws + Z_OFF);
    const int4*  d4 = (const int4*)dst;

    int n = gwave;
    int nbr = (n < N_NODES) ? dst[n * KDEG + a] : 0;
    while (n < N_NODES) {
        const int n2 = n + nwaves;
        int nbr_next = (n2 < N_NODES) ? dst[n2 * KDEG + a] : 0;

        // independent loads: z chunk + dst-row chunk of this lane's neighbor
        float4 v  = z4[(size_t)nbr * 4 + c];
        int4   cv = d4[(size_t)nbr * 4 + c];

        // membership mask: bit b = any(cv == nbr_b), partial over this chunk
        uint32_t m = 0;
        #pragma unroll
        for (int b = 0; b < KDEG; ++b) {
            int vb = __builtin_amdgcn_readlane(nbr, b);
            uint32_t hit = (uint32_t)((cv.x == vb) | (cv.y == vb) |
                                      (cv.z == vb) | (cv.w == vb));
            m |= hit << b;
        }
        // merge the 4 chunks of row a (lanes differing in bits 4,5) — DS
        m |= (uint32_t)__shfl_xor((int)m, 16);
        m |= (uint32_t)__shfl_xor((int)m, 32);
        int cm = row16_sumi(__popc(m));        // sum rowcounts over the 16 a's

        // z reduction over a within each 16-lane row — DPP
        float v0 = row16_sum(v.x);
        float v1 = row16_sum(v.y);
        float v2 = row16_sum(v.z);
        float v3 = row16_sum(v.w);

        if (writer) {
            int j = lane & 3;
            float dsel = (j == 0) ? v0 : (j == 1) ? v1 : (j == 2) ? v2 : v3;
            float val = 0.0625f * dsel + A + (float)cm * (1.f / 256.f) * Bc;
            out[n * NTPL + tl] = val;
        }
        n = n2;
        nbr = nbr_next;
    }
}

// ---------------- fallback path (proven R2 kernels, ws too small) ------------
__global__ void ltfwg_prep(const float* __restrict__ tmpl,
                           const float* __restrict__ tfeat,
                           float* __restrict__ ws) {
    const int t   = blockIdx.x;
    const int tid = threadIdx.x;
    float s = 0.f, ssq = 0.f;
    #pragma unroll
    for (int m = 0; m < MTPL; ++m) {
        float v = tfeat[t * (MTPL * NFEAT) + m * NFEAT + tid];
        s += v;
        ssq += v * v;
    }
    ws[TMEAN_OFF + t * NFEAT + tid] = s * 0.125f;
    __shared__ float red[128];
    red[tid] = ssq;
    __syncthreads();
    for (int o = 64; o > 0; o >>= 1) {
        if (tid < o) red[tid] += red[tid + o];
        __syncthreads();
    }
    if (tid == 0) ws[TSQ_OFF + t] = red[0] * 0.125f;
    if (tid < 64) {
        float v = tmpl[t * 64 + tid];
        float sv = v, sv2 = v * v;
        #pragma unroll
        for (int off = 32; off >= 1; off >>= 1) {
            sv  += __shfl_xor(sv, off);
            sv2 += __shfl_xor(sv2, off);
        }
        if (tid == 0) {
            ws[MCT_OFF + t]  = sv  * (1.f / 64.f);
            ws[MCT2_OFF + t] = sv2 * (1.f / 64.f);
        }
    }
}

__global__ __launch_bounds__(256, 4)
void ltfwg_fallback(const float* __restrict__ x, const int* __restrict__ dst,
                    const float* __restrict__ ws, float* __restrict__ out) {
    const int lane   = threadIdx.x & 63;
    const int wave   = (blockIdx.x * blockDim.x + threadIdx.x) >> 6;
    const int nwaves = (gridDim.x * blockDim.x) >> 6;
    float tm0[NTPL], tm1[NTPL];
    #pragma unroll
    for (int t = 0; t < NTPL; ++t) {
        float2 tv = ((const float2*)(ws + TMEAN_OFF + t * NFEAT))[lane];
        tm0[t] = tv.x;
        tm1[t] = tv.y;
    }
    const int tl = lane & 15;
    const float A  = 0.5f * (ws[TSQ_OFF + tl] + ws[MCT2_OFF + tl]);
    const float Bc = 0.5f - ws[MCT_OFF + tl];
    for (int n = wave; n < N_NODES; n += nwaves) {
        const int nbr = dst[n * KDEG + (lane & 15)];
        float fs0 = 0.f, fs1 = 0.f, sqa = 0.f;
        #pragma unroll
        for (int aa = 0; aa < KDEG; ++aa) {
            int nid = __shfl(nbr, aa);
            float2 fv = ((const float2*)x)[nid * (NFEAT / 2) + lane];
            fs0 += fv.x; fs1 += fv.y;
            sqa += fv.x * fv.x + fv.y * fv.y;
        }
        float dotp[NTPL];
        #pragma unroll
        for (int t = 0; t < NTPL; ++t) dotp[t] = fs0 * tm0[t] + fs1 * tm1[t];
        int nida = __shfl(nbr, lane >> 2);
        int4 cv = ((const int4*)(dst + nida * KDEG))[lane & 3];
        uint32_t m = 0;
        #pragma unroll
        for (int b = 0; b < KDEG; ++b) {
            int vb = __shfl(nbr, b);
            uint32_t hit = (uint32_t)((cv.x == vb) | (cv.y == vb) |
                                      (cv.z == vb) | (cv.w == vb));
            m |= hit << b;
        }
        m |= (uint32_t)__shfl_xor((int)m, 1);
        m |= (uint32_t)__shfl_xor((int)m, 2);
        float cnt = (float)__popc(m);
        #pragma unroll
        for (int off = 32; off >= 1; off >>= 1) {
            sqa += __shfl_xor(sqa, off);
            cnt += __shfl_xor(cnt, off);
            #pragma unroll
            for (int t = 0; t < NTPL; ++t) dotp[t] += __shfl_xor(dotp[t], off);
        }
        float dsel = dotp[0];
        #pragma unroll
        for (int t = 1; t < NTPL; ++t) dsel = (lane == t) ? dotp[t] : dsel;
        if (lane < NTPL) {
            float mC = cnt * (1.0f / 1024.0f);
            out[n * NTPL + lane] = 0.03125f * sqa - 0.0625f * dsel + A + mC * Bc;
        }
    }
}

extern "C" void kernel_launch(void* const* d_in, const int* in_sizes, int n_in,
                              void* d_out, int out_size, void* d_ws, size_t ws_size,
                              hipStream_t stream) {
    const float* x     = (const float*)d_in[0];
    const int*   edge  = (const int*)d_in[1];
    const float* tmpl  = (const float*)d_in[2];
    const float* tfeat = (const float*)d_in[3];
    float* ws  = (float*)d_ws;
    float* out = (float*)d_out;
    const int* dst = edge + (N_NODES * KDEG);

    if (ws_size >= WS_BYTES) {
        ltfwg_zbuild<<<NTILES, 256, 0, stream>>>(x, tmpl, tfeat, ws);
        ltfwg_gather<<<2048, 256, 0, stream>>>(dst, ws, out);
    } else {
        ltfwg_prep<<<NTPL, 128, 0, stream>>>(tmpl, tfeat, ws);
        ltfwg_fallback<<<1024, 256, 0, stream>>>(x, dst, ws, out);
    }
}